// Round 2
// baseline (3688.998 us; speedup 1.0000x reference)
//
#include <hip/hip_runtime.h>
#include <hip/hip_cooperative_groups.h>

namespace cg = cooperative_groups;

// BasicNCA: x:(16,1,512,512) f32, k 3x3, MLP 1->10->1, 16 steps.
// out: (steps+1)*16*512*512 f32 trajectory.
// Single cooperative kernel: grid-stride over pixels each step, grid.sync()
// between steps (stencil halo => grid-wide dependency). This removes the
// 16x kernel launch/drain overhead that dominated R0 (28 us/step measured
// vs ~6 us roofline).

#define NCA_H 512
#define NCA_W 512
#define NCA_HW (NCA_H * NCA_W)
#define NCA_B 16
#define NCA_SLICE (NCA_B * NCA_HW)       // 4194304 floats
#define NCA_GROUPS (NCA_SLICE / 4)       // 1048576 float4-groups
#define NCA_BLOCKS 1024                  // 4 blocks/CU co-resident (cooperative)
#define NCA_THREADS 256

// all lanes load the same address -> force into SGPR
__device__ __forceinline__ float uload(const float* p) {
    float v = *p;
    return __int_as_float(__builtin_amdgcn_readfirstlane(__float_as_int(v)));
}

__global__ __launch_bounds__(NCA_THREADS, 4) void nca_all(
        float* __restrict__ out,
        const float* __restrict__ kc,
        const float* __restrict__ w1g,
        const float* __restrict__ b1g,
        const float* __restrict__ w2g,
        int steps) {
    // stage all 39 weights into scalar registers
    float k00 = uload(kc + 0), k01 = uload(kc + 1), k02 = uload(kc + 2);
    float k10 = uload(kc + 3), k11 = uload(kc + 4), k12 = uload(kc + 5);
    float k20 = uload(kc + 6), k21 = uload(kc + 7), k22 = uload(kc + 8);
    float w1[10], b1[10], w2[10];
#pragma unroll
    for (int o = 0; o < 10; ++o) {
        w1[o] = uload(w1g + o);
        b1[o] = uload(b1g + o);
        w2[o] = uload(w2g + o);
    }

    cg::grid_group grid = cg::this_grid();
    const int tid = blockIdx.x * blockDim.x + threadIdx.x;
    const int nthreads = NCA_BLOCKS * NCA_THREADS;   // 262144

    for (int t = 0; t < steps; ++t) {
        const float* __restrict__ src = out + (size_t)t * NCA_SLICE;
        float* __restrict__ dst = out + (size_t)(t + 1) * NCA_SLICE;

#pragma unroll
        for (int it = 0; it < NCA_GROUPS / (NCA_BLOCKS * NCA_THREADS); ++it) {
            int g = tid + it * nthreads;
            int wq = g & 127;            // W/4 groups per row
            int h  = (g >> 7) & 511;
            int b  = g >> 16;
            int w0 = wq << 2;

            const float* base = src + (size_t)b * NCA_HW;

            float rowv[3][6];
#pragma unroll
            for (int r = 0; r < 3; ++r) {
                int hh = h + r - 1;
                if (hh < 0 || hh >= NCA_H) {
#pragma unroll
                    for (int c = 0; c < 6; ++c) rowv[r][c] = 0.f;
                } else {
                    const float* rp = base + hh * NCA_W + w0;   // 16B aligned
                    float4 c4 = *(const float4*)rp;
                    rowv[r][1] = c4.x; rowv[r][2] = c4.y;
                    rowv[r][3] = c4.z; rowv[r][4] = c4.w;
                    rowv[r][0] = (w0 > 0) ? rp[-1] : 0.f;
                    rowv[r][5] = (w0 + 4 < NCA_W) ? rp[4] : 0.f;
                }
            }

            float4 res;
            float* resp = (float*)&res;
#pragma unroll
            for (int j = 0; j < 4; ++j) {
                float s = 0.f;
                s = fmaf(k00, rowv[0][j], s);
                s = fmaf(k01, rowv[0][j + 1], s);
                s = fmaf(k02, rowv[0][j + 2], s);
                s = fmaf(k10, rowv[1][j], s);
                s = fmaf(k11, rowv[1][j + 1], s);
                s = fmaf(k12, rowv[1][j + 2], s);
                s = fmaf(k20, rowv[2][j], s);
                s = fmaf(k21, rowv[2][j + 1], s);
                s = fmaf(k22, rowv[2][j + 2], s);
                float d = s - 1.0f;
                float gau = __expf(-d * d);
                float acc = 0.f;
#pragma unroll
                for (int o = 0; o < 10; ++o) {
                    float hm = fmaxf(fmaf(w1[o], gau, b1[o]), 0.f);
                    acc = fmaf(w2[o], hm, acc);
                }
                float sig = __fdividef(1.0f, 1.0f + __expf(-acc));
                resp[j] = rowv[1][j + 1] + (sig - 0.5f);
            }

            *(float4*)(dst + (size_t)g * 4) = res;
        }

        if (t + 1 < steps) {
            __threadfence();   // make stores visible across XCDs
            grid.sync();
        }
    }
}

extern "C" void kernel_launch(void* const* d_in, const int* in_sizes, int n_in,
                              void* d_out, int out_size, void* d_ws, size_t ws_size,
                              hipStream_t stream) {
    const float* x  = (const float*)d_in[0];
    float* out = (float*)d_out;

    const int slice = in_sizes[0];                 // 4194304
    int steps = out_size / slice - 1;              // 16

    // slice 0 = initial state
    hipMemcpyAsync(out, x, (size_t)slice * sizeof(float),
                   hipMemcpyDeviceToDevice, stream);

    void* args[] = { (void*)&out, (void*)&d_in[1], (void*)&d_in[2],
                     (void*)&d_in[3], (void*)&d_in[4], (void*)&steps };
    hipLaunchCooperativeKernel((const void*)nca_all,
                               dim3(NCA_BLOCKS), dim3(NCA_THREADS),
                               args, 0, stream);
}

// Round 3
// 1436.718 us; speedup vs baseline: 2.5677x; 2.5677x over previous
//
#include <hip/hip_runtime.h>

// BasicNCA: x:(16,1,512,512) f32, k 3x3, MLP 1->10->1, 16 steps.
// out: (steps+1)*16*512*512 f32 trajectory.
//
// R1 -> R2: cg::grid_group::sync() measured ~225 us/sync (!). Replaced with a
// hand-rolled barrier. Key structural fact: the 16 batch images are fully
// independent (stencil halo is per-image), so we use 16 independent 64-block
// barriers (counter per image, 256B apart) instead of one 1024-block barrier.
// Monotonic counters (target = 64*(t+1)), agent-scope atomics, threadfence
// release/acquire for cross-XCD visibility. Cooperative launch kept ONLY for
// the co-residency guarantee.

#define NCA_H 512
#define NCA_W 512
#define NCA_HW (NCA_H * NCA_W)
#define NCA_B 16
#define NCA_SLICE (NCA_B * NCA_HW)        // 4194304 floats
#define NCA_BLOCKS 1024                   // 4/CU co-resident (verified R1)
#define NCA_THREADS 256
#define BLK_PER_IMG (NCA_BLOCKS / NCA_B)  // 64
#define CNT_STRIDE 64                     // uints between counters (256B)

__device__ __forceinline__ float uload(const float* p) {
    float v = *p;
    return __int_as_float(__builtin_amdgcn_readfirstlane(__float_as_int(v)));
}

__global__ __launch_bounds__(NCA_THREADS, 4) void nca_all(
        float* __restrict__ out,
        const float* __restrict__ kc,
        const float* __restrict__ w1g,
        const float* __restrict__ b1g,
        const float* __restrict__ w2g,
        unsigned int* __restrict__ cnt,
        int steps) {
    // weights -> scalar regs
    float k00 = uload(kc + 0), k01 = uload(kc + 1), k02 = uload(kc + 2);
    float k10 = uload(kc + 3), k11 = uload(kc + 4), k12 = uload(kc + 5);
    float k20 = uload(kc + 6), k21 = uload(kc + 7), k22 = uload(kc + 8);
    float w1[10], b1[10], w2[10];
#pragma unroll
    for (int o = 0; o < 10; ++o) {
        w1[o] = uload(w1g + o);
        b1[o] = uload(b1g + o);
        w2[o] = uload(w2g + o);
    }

    const int b  = blockIdx.x >> 6;        // image 0..15
    const int lb = blockIdx.x & 63;        // local block within image
    unsigned int* mycnt = cnt + b * CNT_STRIDE;

    for (int t = 0; t < steps; ++t) {
        const float* __restrict__ src = out + (size_t)t * NCA_SLICE + (size_t)b * NCA_HW;
        float* __restrict__ dst = out + (size_t)(t + 1) * NCA_SLICE + (size_t)b * NCA_HW;

#pragma unroll
        for (int it = 0; it < NCA_HW / 4 / (BLK_PER_IMG * NCA_THREADS); ++it) {  // 4 iters
            int g = lb * NCA_THREADS + threadIdx.x + it * (BLK_PER_IMG * NCA_THREADS);
            int h  = g >> 7;               // 128 float4-groups per row
            int w0 = (g & 127) << 2;

            float rowv[3][6];
#pragma unroll
            for (int r = 0; r < 3; ++r) {
                int hh = h + r - 1;
                if (hh < 0 || hh >= NCA_H) {
#pragma unroll
                    for (int c = 0; c < 6; ++c) rowv[r][c] = 0.f;
                } else {
                    const float* rp = src + hh * NCA_W + w0;   // 16B aligned
                    float4 c4 = *(const float4*)rp;
                    rowv[r][1] = c4.x; rowv[r][2] = c4.y;
                    rowv[r][3] = c4.z; rowv[r][4] = c4.w;
                    rowv[r][0] = (w0 > 0) ? rp[-1] : 0.f;
                    rowv[r][5] = (w0 + 4 < NCA_W) ? rp[4] : 0.f;
                }
            }

            float4 res;
            float* resp = (float*)&res;
#pragma unroll
            for (int j = 0; j < 4; ++j) {
                float s = 0.f;
                s = fmaf(k00, rowv[0][j], s);
                s = fmaf(k01, rowv[0][j + 1], s);
                s = fmaf(k02, rowv[0][j + 2], s);
                s = fmaf(k10, rowv[1][j], s);
                s = fmaf(k11, rowv[1][j + 1], s);
                s = fmaf(k12, rowv[1][j + 2], s);
                s = fmaf(k20, rowv[2][j], s);
                s = fmaf(k21, rowv[2][j + 1], s);
                s = fmaf(k22, rowv[2][j + 2], s);
                float d = s - 1.0f;
                float gau = __expf(-d * d);
                float acc = 0.f;
#pragma unroll
                for (int o = 0; o < 10; ++o) {
                    float hm = fmaxf(fmaf(w1[o], gau, b1[o]), 0.f);
                    acc = fmaf(w2[o], hm, acc);
                }
                float sig = __fdividef(1.0f, 1.0f + __expf(-acc));
                resp[j] = rowv[1][j + 1] + (sig - 0.5f);
            }

            *(float4*)(dst + (h << 9) + w0) = res;
        }

        if (t + 1 < steps) {
            __syncthreads();
            if (threadIdx.x == 0) {
                __threadfence();   // release: wbl2 -> stores visible at coherence point
                __hip_atomic_fetch_add(mycnt, 1u, __ATOMIC_RELAXED,
                                       __HIP_MEMORY_SCOPE_AGENT);
                const unsigned int target = (unsigned int)(t + 1) * BLK_PER_IMG;
                while (__hip_atomic_load(mycnt, __ATOMIC_RELAXED,
                                         __HIP_MEMORY_SCOPE_AGENT) < target) {
                    __builtin_amdgcn_s_sleep(2);
                }
                __threadfence();   // acquire: inv stale L1/L2 lines
            }
            __syncthreads();
        }
    }
}

extern "C" void kernel_launch(void* const* d_in, const int* in_sizes, int n_in,
                              void* d_out, int out_size, void* d_ws, size_t ws_size,
                              hipStream_t stream) {
    const float* x  = (const float*)d_in[0];
    float* out = (float*)d_out;
    unsigned int* cnt = (unsigned int*)d_ws;

    const int slice = in_sizes[0];                 // 4194304
    int steps = out_size / slice - 1;              // 16

    // zero the barrier counters (d_ws is poisoned 0xAA before every launch)
    hipMemsetAsync(cnt, 0, NCA_B * CNT_STRIDE * sizeof(unsigned int), stream);

    // slice 0 = initial state
    hipMemcpyAsync(out, x, (size_t)slice * sizeof(float),
                   hipMemcpyDeviceToDevice, stream);

    void* args[] = { (void*)&out, (void*)&d_in[1], (void*)&d_in[2],
                     (void*)&d_in[3], (void*)&d_in[4], (void*)&cnt, (void*)&steps };
    hipLaunchCooperativeKernel((const void*)nca_all,
                               dim3(NCA_BLOCKS), dim3(NCA_THREADS),
                               args, 0, stream);
}